// Round 1
// baseline (1816.479 us; speedup 1.0000x reference)
//
#include <hip/hip_runtime.h>

// GADBase diffusion: B=2, H=W=512, 128 iterations of fused diffuse+adjust.
constexpr int Hh = 512, Ww = 512, Bn = 2;
constexpr int SHh = 128, SWw = 128;
constexpr float Lf = 0.24f;
constexpr float Kf = 0.03f;
constexpr float EPSf = 1e-8f;
constexpr int NSTEPS = 128;

constexpr int NPIX = Bn * Hh * Ww;        // 524288
constexpr int CVN  = Bn * (Hh - 1) * Ww;  // 523264
constexpr int CHN  = Bn * Hh * (Ww - 1);  // 523264

// ---------------------------------------------------------------------------
// Kernel 1: edge-stopping coefficients cv, ch from [img, guide0..2] channel-
// mean abs finite differences. Computed once.
// ---------------------------------------------------------------------------
__global__ __launch_bounds__(256) void cvch_kernel(
    const float* __restrict__ img, const float* __restrict__ guide,
    float* __restrict__ cv, float* __restrict__ ch) {
  int idx = blockIdx.x * blockDim.x + threadIdx.x;
  if (idx >= NPIX) return;
  int x = idx & (Ww - 1);
  int y = (idx >> 9) & (Hh - 1);
  int b = idx >> 18;
  const float inv_k2 = 1.0f / (Kf * Kf);
  const float* f0 = img + (size_t)b * Hh * Ww;
  const float* g0 = guide + (size_t)b * 3 * Hh * Ww;
  const float* g1 = g0 + Hh * Ww;
  const float* g2 = g1 + Hh * Ww;
  int p = y * Ww + x;
  float c0 = f0[p], c1 = g0[p], c2 = g1[p], c3 = g2[p];
  if (y < Hh - 1) {
    int q = p + Ww;
    float m = (fabsf(f0[q] - c0) + fabsf(g0[q] - c1) +
               fabsf(g1[q] - c2) + fabsf(g2[q] - c3)) * 0.25f;
    cv[(b * (Hh - 1) + y) * Ww + x] = 1.0f / (1.0f + m * m * inv_k2);
  }
  if (x < Ww - 1) {
    int q = p + 1;
    float m = (fabsf(f0[q] - c0) + fabsf(g0[q] - c1) +
               fabsf(g1[q] - c2) + fabsf(g2[q] - c3)) * 0.25f;
    ch[(b * Hh + y) * (Ww - 1) + x] = 1.0f / (1.0f + m * m * inv_k2);
  }
}

// ---------------------------------------------------------------------------
// Kernel 2: one fused diffuse+adjust step.
// Tile 32x32 per workgroup of 64 threads; each thread owns one 4x4 block so
// the AdaptiveAvgPool block-mean is thread-local.
// ---------------------------------------------------------------------------
constexpr int TILE = 32;

__global__ __launch_bounds__(64) void step_kernel(
    const float* __restrict__ src, float* __restrict__ dst,
    const float* __restrict__ cv, const float* __restrict__ ch,
    const float* __restrict__ source, const float* __restrict__ mask) {
  __shared__ float sI[TILE + 2][TILE + 2 + 1];  // +1 pad vs bank conflicts

  int b = blockIdx.z;
  int ty0 = blockIdx.y * TILE;
  int tx0 = blockIdx.x * TILE;
  const float* I = src + (size_t)b * Hh * Ww;
  int tid = threadIdx.x;

  // Load (TILE+2)^2 halo tile, clamped at image borders (clamped values are
  // never used: boundary flux terms are guarded by global-coordinate checks).
  for (int i = tid; i < (TILE + 2) * (TILE + 2); i += 64) {
    int ly = i / (TILE + 2), lx = i % (TILE + 2);
    int gy = ty0 + ly - 1; gy = max(0, min(Hh - 1, gy));
    int gx = tx0 + lx - 1; gx = max(0, min(Ww - 1, gx));
    sI[ly][lx] = I[gy * Ww + gx];
  }
  __syncthreads();

  // Thread -> one 4x4 block (8x8 blocks in a 32x32 tile).
  int bby = tid >> 3, bbx = tid & 7;
  int py0 = bby * 4, px0 = bbx * 4;
  int gy0 = ty0 + py0, gx0 = tx0 + px0;
  const float* cvb = cv + (size_t)b * (Hh - 1) * Ww;
  const float* chb = ch + (size_t)b * Hh * (Ww - 1);

  float v[4][4];
  float sum = 0.0f;
#pragma unroll
  for (int dy = 0; dy < 4; ++dy) {
    int y = gy0 + dy;
    int ly = py0 + dy + 1;
#pragma unroll
    for (int dx = 0; dx < 4; ++dx) {
      int x = gx0 + dx;
      int lx = px0 + dx + 1;
      float c = sI[ly][lx];
      float acc = c;
      if (y < Hh - 1) acc += Lf * cvb[y * Ww + x] * (sI[ly + 1][lx] - c);
      if (y > 0)      acc -= Lf * cvb[(y - 1) * Ww + x] * (c - sI[ly - 1][lx]);
      if (x < Ww - 1) acc += Lf * chb[y * (Ww - 1) + x] * (sI[ly][lx + 1] - c);
      if (x > 0)      acc -= Lf * chb[y * (Ww - 1) + x - 1] * (c - sI[ly][lx - 1]);
      v[dy][dx] = acc;
      sum += acc;
    }
  }

  // Adjust: block mean -> ratio (or 1 where mask_lr > 0.5).
  float mean = sum * (1.0f / 16.0f);
  int sy = gy0 >> 2, sx = gx0 >> 2;
  int sidx = (b * SHh + sy) * SWw + sx;
  float ratio = (mask[sidx] > 0.5f) ? 1.0f : source[sidx] / (mean + EPSf);

  float* D = dst + (size_t)b * Hh * Ww;
#pragma unroll
  for (int dy = 0; dy < 4; ++dy) {
    float4 o = make_float4(v[dy][0] * ratio, v[dy][1] * ratio,
                           v[dy][2] * ratio, v[dy][3] * ratio);
    *reinterpret_cast<float4*>(&D[(gy0 + dy) * Ww + gx0]) = o;
  }
}

// ---------------------------------------------------------------------------
extern "C" void kernel_launch(void* const* d_in, const int* in_sizes, int n_in,
                              void* d_out, int out_size, void* d_ws, size_t ws_size,
                              hipStream_t stream) {
  const float* guide  = (const float*)d_in[0];
  const float* ybic   = (const float*)d_in[1];
  const float* source = (const float*)d_in[2];
  const float* mask   = (const float*)d_in[3];

  float* out   = (float*)d_out;
  float* ypred = out;                 // 524288
  float* cv    = out + NPIX;          // 523264
  float* ch    = out + NPIX + CVN;    // 523264
  float* wsbuf = (float*)d_ws;        // 2 MB ping buffer

  cvch_kernel<<<dim3((NPIX + 255) / 256), dim3(256), 0, stream>>>(ybic, guide, cv, ch);

  dim3 grid(Ww / TILE, Hh / TILE, Bn);  // 16 x 16 x 2 = 512 WGs
  const float* srcp = ybic;
  for (int it = 0; it < NSTEPS; ++it) {
    // even iters -> ws buffer, odd iters -> d_out y_pred slot.
    // Last iter (127, odd) lands in d_out; input is never mutated.
    float* dstp = (it & 1) ? ypred : wsbuf;
    step_kernel<<<grid, dim3(64), 0, stream>>>(srcp, dstp, cv, ch, source, mask);
    srcp = dstp;
  }
}